// Round 5
// baseline (624.758 us; speedup 1.0000x reference)
//
#include <hip/hip_runtime.h>
#include <hip/hip_bf16.h>

#define HID 64

// ---------------------------------------------------------------------------
// Node kernel: per-node linear projections, packed for single-line gathers.
//   spack[2n]   = x0[n] @ Wsp + bsp   (float4)        src-side pair params
//   spack[2n+1] = { x[n] @ Wsg + bsg, 0, 0, 0 }       src-side gate scalar
//   dpack[2n]   = x0[n] @ Wdp          (float4)        dst-side pair params
//   dpack[2n+1] = { x[n] @ Wdg + bdg, 0, 0, 0 }       dst-side gate scalar
// 32B slot per node per side -> the edge kernel's two reads (float4 @ +0,
// float @ +16) always hit the SAME cache line: 2 random lines/edge, not 4.
// ---------------------------------------------------------------------------
__global__ __launch_bounds__(256) void nbo_node_kernel(
    const float* __restrict__ x, const float* __restrict__ x0,
    const float* __restrict__ Wsg, const float* __restrict__ bsg,
    const float* __restrict__ Wdg, const float* __restrict__ bdg,
    const float* __restrict__ Wsp, const float* __restrict__ bsp,
    const float* __restrict__ Wdp,
    float4* __restrict__ spack, float4* __restrict__ dpack, int N)
{
    __shared__ float4 s_wsg[16];   // Wsg as 16 float4
    __shared__ float4 s_wdg[16];   // Wdg
    __shared__ float4 s_wsp[64];   // Wsp row-major: row i -> float4 of 4 outputs
    __shared__ float4 s_wdp[64];   // Wdp

    const int tid = threadIdx.x;
    if (tid < 16) {
        s_wsg[tid] = ((const float4*)Wsg)[tid];
        s_wdg[tid] = ((const float4*)Wdg)[tid];
    }
    if (tid < 64) {
        s_wsp[tid] = ((const float4*)Wsp)[tid];
        s_wdp[tid] = ((const float4*)Wdp)[tid];
    }
    __syncthreads();

    const int n = blockIdx.x * 256 + tid;
    if (n >= N) return;

    const float4* xv  = (const float4*)(x  + (size_t)n * HID);
    const float4* x0v = (const float4*)(x0 + (size_t)n * HID);

    float  asg = 0.f, adg = 0.f;
    float4 asp = make_float4(0.f, 0.f, 0.f, 0.f);
    float4 adp = make_float4(0.f, 0.f, 0.f, 0.f);

#pragma unroll
    for (int j = 0; j < 16; ++j) {
        const float4 a = xv[j];
        const float4 b = x0v[j];
        const float4 g = s_wsg[j];
        const float4 h = s_wdg[j];
        asg += a.x * g.x + a.y * g.y + a.z * g.z + a.w * g.w;
        adg += a.x * h.x + a.y * h.y + a.z * h.z + a.w * h.w;
#pragma unroll
        for (int c = 0; c < 4; ++c) {
            const float bx = (&b.x)[c];
            const float4 sp = s_wsp[4 * j + c];
            const float4 dp = s_wdp[4 * j + c];
            asp.x += bx * sp.x; asp.y += bx * sp.y;
            asp.z += bx * sp.z; asp.w += bx * sp.w;
            adp.x += bx * dp.x; adp.y += bx * dp.y;
            adp.z += bx * dp.z; adp.w += bx * dp.w;
        }
    }

    spack[2 * n]     = make_float4(asp.x + bsp[0], asp.y + bsp[1],
                                   asp.z + bsp[2], asp.w + bsp[3]);
    spack[2 * n + 1] = make_float4(asg + bsg[0], 0.f, 0.f, 0.f);
    dpack[2 * n]     = adp;
    dpack[2 * n + 1] = make_float4(adg + bdg[0], 0.f, 0.f, 0.f);
}

// ---------------------------------------------------------------------------
// Edge kernel: FOUR edges per thread.
//   - One coalesced float4 load of bl[4t..4t+3] + int4 src/dst issued up
//     front (3 independent loads); the single bl-latency stall is amortized
//     over 4 edges and hidden by other waves (32 waves/CU).
//   - y-row stream is GUARDED by r <= 4.0 with PLAIN loads (no nontemporal —
//     R2's regression is suspected to be the nt flag defeating line reuse,
//     not the branch). Skipped rows (~20%) never touch HBM: -80 MB.
//   - spack/dpack packing: 2 random lines per edge instead of 4 (R4).
//   m  = esrc[s] + edst[d] + y@Weg + beg ;  bo = sigmoid(m)
//   f_rep = exp(a0 - P1*r), P1 = exp(a1)   (folded: 5 expf total)
//   f_att = exp(a2 - P3*r), P3 = exp(a3)
//   V  = cutoff(r) * (f_rep - bo * f_att)
//   atomicAdd(atomwise[d], V);  block-reduce V -> atomicAdd(energy, sum/N)
// out[0] = energy, out[1..N] = atomwise_energy (both pre-zeroed).
// ---------------------------------------------------------------------------
__global__ __launch_bounds__(256) void nbo_edge_kernel(
    const float* __restrict__ y, const float* __restrict__ bl,
    const int* __restrict__ src, const int* __restrict__ dst,
    const float* __restrict__ Weg, const float* __restrict__ beg,
    const float4* __restrict__ spack, const float4* __restrict__ dpack,
    float* __restrict__ out, int E, float invN)
{
    __shared__ float4 s_weg[16];
    const int tid = threadIdx.x;
    if (tid < 16) s_weg[tid] = ((const float4*)Weg)[tid];
    __syncthreads();

    const int t  = blockIdx.x * 256 + tid;
    const int e0 = t * 4;
    float V = 0.f;

    if (e0 < E) {
        // Coalesced per-edge scalars: 3 independent 16B loads, issued together.
        const float4 r4 = *(const float4*)(bl  + e0);
        const int4   s4 = *(const int4*)(src + e0);
        const int4   d4 = *(const int4*)(dst + e0);
        const float  begv = beg[0];

#pragma unroll
        for (int k = 0; k < 4; ++k) {
            const int e = e0 + k;
            if (e >= E) break;
            const float r = (&r4.x)[k];
            // cutoff == 0 beyond 4.0: edge contributes exactly 0 -> skip all
            if (r > 4.0f) continue;
            const int s = (&s4.x)[k];
            const int d = (&d4.x)[k];

            // y[e] @ Weg  (16 x float4, plain cached loads)
            const float4* yv = (const float4*)(y + (size_t)e * HID);
            float dotv = 0.f;
#pragma unroll
            for (int j = 0; j < 16; ++j) {
                const float4 a = yv[j];
                const float4 w = s_weg[j];
                dotv += a.x * w.x + a.y * w.y + a.z * w.z + a.w * w.w;
            }

            // One 32B slot per side: float4 @ +0 and float @ +16 share a line.
            const float4 p1 = spack[2 * s];
            const float  es = ((const float*)(spack + 2 * s + 1))[0];
            const float4 p2 = dpack[2 * d];
            const float  ed = ((const float*)(dpack + 2 * d + 1))[0];

            const float m  = es + ed + dotv + begv;
            const float bo = 1.0f / (1.0f + __expf(-m));

            // Fold amplitude exp into the decay exp: P0*exp(-P1*r)=exp(a0-P1*r)
            const float P1 = __expf(p1.y + p2.y);
            const float P3 = __expf(p1.w + p2.w);
            const float f_rep = __expf(p1.x + p2.x - P1 * r);
            const float f_att = __expf(p1.z + p2.z - P3 * r);

            // cutoff: D=0.1, R=3.9 ; pi/(2D) = pi/0.2
            const float cut = (r < 3.8f)
                ? 1.0f
                : (0.5f - 0.5f * __sinf(15.707963267948966f * (r - 3.9f)));

            const float Ve = cut * (f_rep - bo * f_att);
            V += Ve;
            atomicAdd(out + 1 + d, Ve);
        }
    }

    // Block reduction of V for the energy mean (one atomic per block).
#pragma unroll
    for (int off = 32; off > 0; off >>= 1)
        V += __shfl_down(V, off);

    __shared__ float s_wsum[4];
    const int wid  = tid >> 6;
    const int lane = tid & 63;
    if (lane == 0) s_wsum[wid] = V;
    __syncthreads();
    if (tid == 0) {
        const float bsum = s_wsum[0] + s_wsum[1] + s_wsum[2] + s_wsum[3];
        atomicAdd(out, bsum * invN);
    }
}

extern "C" void kernel_launch(void* const* d_in, const int* in_sizes, int n_in,
                              void* d_out, int out_size, void* d_ws, size_t ws_size,
                              hipStream_t stream) {
    const float* x   = (const float*)d_in[0];
    const float* x0  = (const float*)d_in[1];
    const float* y   = (const float*)d_in[2];
    const float* bl  = (const float*)d_in[3];
    const int*   src = (const int*)d_in[4];
    const int*   dst = (const int*)d_in[5];
    const float* Wsg = (const float*)d_in[6];
    const float* bsg = (const float*)d_in[7];
    const float* Wdg = (const float*)d_in[8];
    const float* bdg = (const float*)d_in[9];
    const float* Weg = (const float*)d_in[10];
    const float* beg = (const float*)d_in[11];
    const float* Wsp = (const float*)d_in[12];
    const float* bsp = (const float*)d_in[13];
    const float* Wdp = (const float*)d_in[14];

    const int N = in_sizes[0] / HID;
    const int E = in_sizes[3];

    float* out = (float*)d_out;
    float* ws  = (float*)d_ws;

    // ws layout: spack[N] (2 float4/node) | dpack[N] (2 float4/node) = 64B/node
    float4* w_spack = (float4*)ws;
    float4* w_dpack = (float4*)ws + 2 * (size_t)N;

    // d_out is poisoned 0xAA before every timed launch; we accumulate into it.
    (void)hipMemsetAsync(d_out, 0, (size_t)out_size * sizeof(float), stream);

    nbo_node_kernel<<<(N + 255) / 256, 256, 0, stream>>>(
        x, x0, Wsg, bsg, Wdg, bdg, Wsp, bsp, Wdp,
        w_spack, w_dpack, N);

    const int nthreads_e = (E + 3) / 4;
    nbo_edge_kernel<<<(nthreads_e + 255) / 256, 256, 0, stream>>>(
        y, bl, src, dst, Weg, beg,
        w_spack, w_dpack,
        out, E, 1.0f / (float)N);
}